// Round 6
// baseline (341.401 us; speedup 1.0000x reference)
//
#include <hip/hip_runtime.h>
#include <hip/hip_cooperative_groups.h>

namespace cg = cooperative_groups;

#define B 8
#define N 2048
#define KF 256
#define DF 64
#define LOG2E 1.44269504088896340736f
#define NR 2049   // prefix-table rows per batch (row 2048 = total/zero row)

typedef __attribute__((ext_vector_type(8))) short short8;   // 8 bf16 (4 VGPRs)
typedef __attribute__((ext_vector_type(4))) float float4v;  // MFMA C/D frag

__device__ __forceinline__ float fexp2(float x) {
#if __has_builtin(__builtin_amdgcn_exp2f)
    return __builtin_amdgcn_exp2f(x);
#else
    return exp2f(x);
#endif
}
__device__ __forceinline__ float eluf(float x) {
    return x > 0.f ? x : fexp2(x * LOG2E) - 1.0f;
}
// float -> bf16 bits, round-half-up
__device__ __forceinline__ short bf16r(float x) {
    unsigned u = __float_as_uint(x);
    return (short)((u + 0x8000u) >> 16);
}
// monotone float -> sortable uint key (order-preserving for all finite values)
__device__ __forceinline__ unsigned sortkey(float x) {
    unsigned u = __float_as_uint(x);
    return u ^ (((unsigned)((int)u >> 31)) | 0x80000000u);
}
#define DOT4(c, u, p) \
    p = fmaf(c.x, u.x, fmaf(c.y, u.y, fmaf(c.z, u.z, fmaf(c.w, u.w, p))));

// ---- Single cooperative kernel: 512 blocks x 256 thr, 5 phases.
// P1: Wh=h@W (MFMA) + f1/f2 + qpack        [verified k_wh body]
// P2: ranks + denominators (no atomics)    [verified k_rank math]
// P3: segment sums of g*Wh / gs*Wh         [verified k_seg math]
// P4: prefix tables SSg/PSgs               [verified k_tab body]
// P5: gather + elu output                  [verified k_out body]
// grid.sync() between phases replaces 4 kernel-launch boundaries. ----
__global__ __launch_bounds__(256, 2) void mega(
        const float* __restrict__ h, const float* __restrict__ W,
        const float* __restrict__ a, float* __restrict__ out,
        float* __restrict__ Wh, float* __restrict__ f1, float* __restrict__ f2,
        float4* __restrict__ qpack, int* __restrict__ tIdx,
        int* __restrict__ si, float* __restrict__ gA, float* __restrict__ gsA,
        float* __restrict__ segG, float* __restrict__ segGs,
        float* __restrict__ SSg, float* __restrict__ PSgs) {
    cg::grid_group grid = cg::this_grid();
    __shared__ __align__(16) unsigned char smem[34816];   // phase union
    int t = threadIdx.x;
    int bid = blockIdx.x;

    // ================= P1: Wh + f1/f2 + qpack =================
    {
        short* lwt  = (short*)smem;               // [64 n][256 k] bf16 W^T (32 KB)
        float* lv   = (float*)(smem + 32768);     // [2][256] v1,v2 (2 KB)
        float* lred = (float*)smem;               // B: [4 wv][16*66] (16.9 KB)
        float* lp   = (float*)(smem + 16896);     // B: [2][4][16]

        int wv = t >> 6, lane = t & 63;
        int n15 = lane & 15, q = lane >> 4;
        int bx = bid;

        const float* hr = h + ((long)bx * 32 + n15) * KF + wv * 64 + q * 8;
        float4 c0 = *(const float4*)(hr);
        float4 c1 = *(const float4*)(hr + 4);
        float4 c2 = *(const float4*)(hr + 32);
        float4 c3 = *(const float4*)(hr + 36);

        {   // in-block W prep: thread t owns W row k=t
            const float4* wr4 = (const float4*)(W + t * DF);
            float s1 = 0.f, s2 = 0.f;
            #pragma unroll
            for (int c = 0; c < 16; c++) {
                float4 w4 = wr4[c];
                float4 a1v = *(const float4*)(a + 4 * c);
                float4 a2v = *(const float4*)(a + DF + 4 * c);
                lwt[(4 * c + 0) * 256 + t] = bf16r(w4.x);
                lwt[(4 * c + 1) * 256 + t] = bf16r(w4.y);
                lwt[(4 * c + 2) * 256 + t] = bf16r(w4.z);
                lwt[(4 * c + 3) * 256 + t] = bf16r(w4.w);
                s1 = fmaf(w4.x, a1v.x, fmaf(w4.y, a1v.y, fmaf(w4.z, a1v.z, fmaf(w4.w, a1v.w, s1))));
                s2 = fmaf(w4.x, a2v.x, fmaf(w4.y, a2v.y, fmaf(w4.z, a2v.z, fmaf(w4.w, a2v.w, s2))));
            }
            lv[t] = s1;
            lv[256 + t] = s2;
        }
        __syncthreads();

        const short* bq = lwt + n15 * 256 + wv * 64 + q * 8;
        short8 s0b0 = *(const short8*)(bq);
        short8 s0b1 = *(const short8*)(bq + 16 * 256);
        short8 s0b2 = *(const short8*)(bq + 32 * 256);
        short8 s0b3 = *(const short8*)(bq + 48 * 256);
        short8 s1b0 = *(const short8*)(bq + 32);
        short8 s1b1 = *(const short8*)(bq + 16 * 256 + 32);
        short8 s1b2 = *(const short8*)(bq + 32 * 256 + 32);
        short8 s1b3 = *(const short8*)(bq + 48 * 256 + 32);
        const float* vv = lv + wv * 64 + q * 8;
        float4 u00 = *(const float4*)(vv);
        float4 u01 = *(const float4*)(vv + 4);
        float4 u10 = *(const float4*)(vv + 32);
        float4 u11 = *(const float4*)(vv + 36);
        float4 x00 = *(const float4*)(vv + 256);
        float4 x01 = *(const float4*)(vv + 256 + 4);
        float4 x10 = *(const float4*)(vv + 256 + 32);
        float4 x11 = *(const float4*)(vv + 256 + 36);
        __syncthreads();   // lwt/lv dead; lred region reusable

        #pragma unroll
        for (int rt = 0; rt < 2; rt++) {
            float4 m0, m1, m2, m3;
            if (rt < 1) {
                const float* hn = hr + 16 * KF;
                m0 = *(const float4*)(hn);
                m1 = *(const float4*)(hn + 4);
                m2 = *(const float4*)(hn + 32);
                m3 = *(const float4*)(hn + 36);
            }
            float p1 = 0.f, p2 = 0.f;
            DOT4(c0, u00, p1) DOT4(c1, u01, p1) DOT4(c2, u10, p1) DOT4(c3, u11, p1)
            DOT4(c0, x00, p2) DOT4(c1, x01, p2) DOT4(c2, x10, p2) DOT4(c3, x11, p2)

            short8 af0 = { bf16r(c0.x), bf16r(c0.y), bf16r(c0.z), bf16r(c0.w),
                           bf16r(c1.x), bf16r(c1.y), bf16r(c1.z), bf16r(c1.w) };
            short8 af1 = { bf16r(c2.x), bf16r(c2.y), bf16r(c2.z), bf16r(c2.w),
                           bf16r(c3.x), bf16r(c3.y), bf16r(c3.z), bf16r(c3.w) };
            float4v acc0 = {0.f, 0.f, 0.f, 0.f}, acc1 = acc0, acc2 = acc0, acc3 = acc0;
            acc0 = __builtin_amdgcn_mfma_f32_16x16x32_bf16(af0, s0b0, acc0, 0, 0, 0);
            acc0 = __builtin_amdgcn_mfma_f32_16x16x32_bf16(af1, s1b0, acc0, 0, 0, 0);
            acc1 = __builtin_amdgcn_mfma_f32_16x16x32_bf16(af0, s0b1, acc1, 0, 0, 0);
            acc1 = __builtin_amdgcn_mfma_f32_16x16x32_bf16(af1, s1b1, acc1, 0, 0, 0);
            acc2 = __builtin_amdgcn_mfma_f32_16x16x32_bf16(af0, s0b2, acc2, 0, 0, 0);
            acc2 = __builtin_amdgcn_mfma_f32_16x16x32_bf16(af1, s1b2, acc2, 0, 0, 0);
            acc3 = __builtin_amdgcn_mfma_f32_16x16x32_bf16(af0, s0b3, acc3, 0, 0, 0);
            acc3 = __builtin_amdgcn_mfma_f32_16x16x32_bf16(af1, s1b3, acc3, 0, 0, 0);

            #define STASH(nb, A)                                                  \
                {                                                                 \
                    _Pragma("unroll")                                             \
                    for (int r = 0; r < 4; r++)                                   \
                        lred[wv * 1056 + (q * 4 + r) * 66 + nb * 16 + n15] = A[r]; \
                }
            STASH(0, acc0) STASH(1, acc1) STASH(2, acc2) STASH(3, acc3)
            #undef STASH
            p1 += __shfl_xor(p1, 16, 64); p1 += __shfl_xor(p1, 32, 64);
            p2 += __shfl_xor(p2, 16, 64); p2 += __shfl_xor(p2, 32, 64);
            if (q == 0) { lp[wv * 16 + n15] = p1; lp[64 + wv * 16 + n15] = p2; }
            __syncthreads();

            long i0 = (long)bx * 32 + rt * 16;
            int d = t & 63, ig = t >> 6;
            int bb = (int)(i0 >> 11);
            int il = (int)(i0 & (N - 1));
            float s0 = 0.f, s1 = 0.f, s2 = 0.f, s3 = 0.f;
            #pragma unroll
            for (int w = 0; w < 4; w++) {
                const float* lr = lred + w * 1056 + (ig * 4) * 66 + d;
                s0 += lr[0]; s1 += lr[66]; s2 += lr[132]; s3 += lr[198];
            }
            float* wp = Wh + ((long)bb * N + il + ig * 4) * DF + d;
            wp[0]      = s0;
            wp[DF]     = s1;
            wp[2 * DF] = s2;
            wp[3 * DF] = s3;

            if (t < 16) {
                float v1 = lp[t] + lp[16 + t] + lp[32 + t] + lp[48 + t];
                f1[i0 + t] = v1;
                // same terms/order as the f2 path below -> bitwise-identical
                float v2 = lp[64 + t] + lp[80 + t] + lp[96 + t] + lp[112 + t];
                float4 qe;
                qe.x = __uint_as_float(sortkey(v1));
                qe.y = __uint_as_float(sortkey(v2));
                qe.z = fexp2(v1 * LOG2E);
                qe.w = fexp2(v1 * 0.2f * LOG2E);
                qpack[i0 + t] = qe;
            } else if (t < 32) {
                int tt = t + 48;   // 64 + (t-16)
                f2[i0 + t - 16] = lp[tt] + lp[16 + tt] + lp[32 + tt] + lp[48 + tt];
            }
            __syncthreads();
            c0 = m0; c1 = m1; c2 = m2; c3 = m3;
        }
    }
    grid.sync();

    // ================= P2: ranks + denominators (256 active blocks) ======
    if (bid < 256) {
        float* rS1  = (float*)smem;           // [4][64]
        float* rS1s = rS1 + 256;
        int*   rC2  = (int*)(rS1s + 256);
        int*   rC3  = rC2 + 256;

        int b = bid >> 5, wnd = bid & 31;
        int base = wnd * 64;
        int jl = t & 63, w = t >> 6;          // w = wave id (0..3)
        int j = base + jl;
        float f1j = f1[(long)b * N + j];
        float f2j = f2[(long)b * N + j];
        unsigned u2j   = sortkey(f2j);
        unsigned vkNf2 = sortkey(-f2j);       // S-sum split: f1_p < -f2_j
        unsigned vkNf1 = sortkey(-f1j);       // threshold:   f2_p < -f1_j

        int c2 = 0, c3 = 0;
        float S1 = 0.f, S1s = 0.f;
        #pragma unroll
        for (int half = 0; half < 2; half++) {
            int c = w + half * 4;             // chunk 0..7, wave-uniform
            const float4* qp = qpack + (long)b * N + c * 256;
            #pragma unroll 8
            for (int x = 0; x < 256; x++) {
                float4 e = qp[x];
                unsigned u1p = __float_as_uint(e.x);
                unsigned u2p = __float_as_uint(e.y);
                int p = c * 256 + x;
                c2 += (u2p < u2j || (u2p == u2j && p < j)) ? 1 : 0;
                c3 += (u2p < vkNf1) ? 1 : 0;
                bool cc = u1p < vkNf2;
                S1  += cc ? 0.f : e.z;
                S1s += cc ? e.w : 0.f;
            }
        }
        rC2[t] = c2; rC3[t] = c3; rS1[t] = S1; rS1s[t] = S1s;
        __syncthreads();

        if (t < 64) {                          // jl == t, j = base + t
            int rank = 0, ti = 0;
            float s1 = 0.f, s1s = 0.f;
            #pragma unroll
            for (int k = 0; k < 4; k++) {
                rank += rC2[k * 64 + t]; ti += rC3[k * 64 + t];
                s1 += rS1[k * 64 + t];   s1s += rS1s[k * 64 + t];
            }
            float E2  = fexp2(f2j * LOG2E);
            float E2s = fexp2(f2j * 0.2f * LOG2E);
            float rr = 1.0f / (E2 * s1 + E2s * s1s);
            tIdx[(long)b * N + j] = ti;
            si [(long)b * N + rank] = j;       // scatter: sorted order
            gA [(long)b * N + rank] = E2 * rr;
            gsA[(long)b * N + rank] = E2s * rr;
        }
    }
    grid.sync();

    // ================= P3: segment sums (512 = 8 b x 64 seg) =============
    {
        float* pp  = (float*)smem;             // [4][64]
        float* pps = pp + 256;
        int b = bid >> 6, seg = bid & 63;
        int d = t & 63, x4 = t >> 6;
        const float* whb = Wh + (((long)b) << 11) * DF;
        long bN = (long)b * N;
        float sg = 0.f, sgs = 0.f;
        #pragma unroll
        for (int x = 0; x < 8; x++) {
            int p = seg * 32 + x4 * 8 + x;
            int r = si[bN + p];
            float wv = whb[r * DF + d];
            sg  = fmaf(gA[bN + p],  wv, sg);
            sgs = fmaf(gsA[bN + p], wv, sgs);
        }
        pp[x4 * 64 + d] = sg; pps[x4 * 64 + d] = sgs;
        __syncthreads();
        if (t < 64) {
            segG [(b * 64 + seg) * DF + t] = pp[t] + pp[64 + t] + pp[128 + t] + pp[192 + t];
            segGs[(b * 64 + seg) * DF + t] = pps[t] + pps[64 + t] + pps[128 + t] + pps[192 + t];
        }
    }
    grid.sync();

    // ================= P4: prefix tables (verified k_tab body) ===========
    {
        float* lPG  = (float*)smem;            // 6 x [4][64]
        float* lPGs = lPG + 256;
        float* lTG  = lPGs + 256;
        float* lTGs = lTG + 256;
        float* wG   = lTGs + 256;
        float* wGs  = wG + 256;
        int d = t & 63, sub = t >> 6;
        int b = bid >> 6, seg = bid & 63;

        const float* sgb  = segG  + (b * 64) * DF + d;
        const float* sgsb = segGs + (b * 64) * DF + d;
        float pg = 0.f, pgs = 0.f, tg = 0.f, tgs = 0.f;
        #pragma unroll
        for (int k = 0; k < 16; k++) {
            int s = sub * 16 + k;
            float vg = sgb[s * DF], vgs = sgsb[s * DF];
            tg += vg; tgs += vgs;
            if (s < seg) { pg += vg; pgs += vgs; }
        }
        lPG[sub * 64 + d] = pg; lPGs[sub * 64 + d] = pgs;
        lTG[sub * 64 + d] = tg; lTGs[sub * 64 + d] = tgs;

        int p0 = seg * 32 + sub * 8;
        const int*   sib = si  + (long)b * N;
        const float* ga  = gA  + (long)b * N;
        const float* gsa = gsA + (long)b * N;
        const float* whb = Wh + (((long)b) << 11) * DF;
        float rows[8], gv[8], gsv[8];
        float sg = 0.f, sgs = 0.f;
        #pragma unroll
        for (int x = 0; x < 8; x++) {
            int p = p0 + x;
            int r = sib[p];
            float wv = whb[r * DF + d];
            rows[x] = wv; gv[x] = ga[p]; gsv[x] = gsa[p];
            sg  = fmaf(gv[x],  wv, sg);
            sgs = fmaf(gsv[x], wv, sgs);
        }
        wG[sub * 64 + d] = sg; wGs[sub * 64 + d] = sgs;
        __syncthreads();

        float totG   = lTG[d] + lTG[64 + d] + lTG[128 + d] + lTG[192 + d];
        float baseG  = lPG[d] + lPG[64 + d] + lPG[128 + d] + lPG[192 + d];
        float baseGs = lPGs[d] + lPGs[64 + d] + lPGs[128 + d] + lPGs[192 + d];
        #pragma unroll
        for (int k = 0; k < 3; k++) {
            if (k < sub) { baseG += wG[k * 64 + d]; baseGs += wGs[k * 64 + d]; }
        }

        float* ssb = SSg  + ((long)b * NR) * DF + d;
        float* psb = PSgs + ((long)b * NR) * DF + d;
        float rg = baseG, rgs = baseGs;
        #pragma unroll
        for (int x = 0; x < 8; x++) {
            long p = p0 + x;
            ssb[p * DF] = totG - rg;
            psb[p * DF] = rgs;
            rg  = fmaf(gv[x],  rows[x], rg);
            rgs = fmaf(gsv[x], rows[x], rgs);
        }
        if (seg == 63 && sub == 3) {
            ssb[2048L * DF] = 0.f;             // exact zero suffix
            psb[2048L * DF] = rgs;             // full prefix total
        }
    }
    grid.sync();

    // ================= P5: gather + elu output (32-row windows) ==========
    {
        int b = bid >> 6, wnd = bid & 63;
        int i0 = wnd * 32;
        int rr = t >> 6, d = t & 63;
        const float* sgB = SSg  + ((long)b * NR) * DF + d;
        const float* pgB = PSgs + ((long)b * NR) * DF + d;
        float* ob = out + ((long)b * N + i0) * DF + d;
        #pragma unroll
        for (int kk = 0; kk < 8; kk++) {
            int r = rr + kk * 4;
            int ti = tIdx[(long)b * N + i0 + r];     // wave-uniform
            float v = f1[(long)b * N + i0 + r];
            float e1  = fexp2(v * LOG2E);
            float e1s = fexp2(v * 0.2f * LOG2E);
            float x = e1 * sgB[(long)ti * DF] + e1s * pgB[(long)ti * DF];
            ob[(long)r * DF] = eluf(x);
        }
    }
}

extern "C" void kernel_launch(void* const* d_in, const int* in_sizes, int n_in,
                              void* d_out, int out_size, void* d_ws, size_t ws_size,
                              hipStream_t stream) {
    const float* h = (const float*)d_in[0];
    const float* W = (const float*)d_in[1];
    const float* a = (const float*)d_in[2];
    float* out = (float*)d_out;

    char* ws = (char*)d_ws;
    const size_t NB = (size_t)B * N;          // 16384 rows
    size_t off = 0;
    float*  Wh    = (float*) (ws + off); off += NB * DF * sizeof(float);   // 4 MB
    float*  f1    = (float*) (ws + off); off += NB * sizeof(float);
    float*  f2    = (float*) (ws + off); off += NB * sizeof(float);
    int*    tIdx  = (int*)   (ws + off); off += NB * sizeof(int);
    int*    si    = (int*)   (ws + off); off += NB * sizeof(int);
    float*  gA    = (float*) (ws + off); off += NB * sizeof(float);
    float*  gsA   = (float*) (ws + off); off += NB * sizeof(float);
    float4* qpack = (float4*)(ws + off); off += NB * sizeof(float4);       // 256 KB
    float*  segG  = (float*) (ws + off); off += (size_t)B * 64 * DF * sizeof(float); // 128 KB
    float*  segGs = (float*) (ws + off); off += (size_t)B * 64 * DF * sizeof(float); // 128 KB
    float*  SSg   = (float*) (ws + off); off += (size_t)B * NR * DF * sizeof(float); // 4.2 MB
    float*  PSgs  = (float*) (ws + off); off += (size_t)B * NR * DF * sizeof(float); // 4.2 MB
    (void)off; (void)ws_size;

    void* args[] = { (void*)&h, (void*)&W, (void*)&a, (void*)&out,
                     (void*)&Wh, (void*)&f1, (void*)&f2, (void*)&qpack,
                     (void*)&tIdx, (void*)&si, (void*)&gA, (void*)&gsA,
                     (void*)&segG, (void*)&segGs, (void*)&SSg, (void*)&PSgs };
    hipLaunchCooperativeKernel((const void*)mega, dim3(512), dim3(256),
                               args, 0, stream);
}

// Round 7
// 112.183 us; speedup vs baseline: 3.0433x; 3.0433x over previous
//
#include <hip/hip_runtime.h>

#define B 8
#define N 2048
#define KF 256
#define DF 64
#define LOG2E 1.44269504088896340736f
#define NR 2049   // Rarr rows per batch (position 2048 = "all prefix")

typedef __attribute__((ext_vector_type(8))) short short8;   // 8 bf16 (4 VGPRs)
typedef __attribute__((ext_vector_type(4))) float float4v;  // MFMA C/D frag

__device__ __forceinline__ float fexp2(float x) {
#if __has_builtin(__builtin_amdgcn_exp2f)
    return __builtin_amdgcn_exp2f(x);
#else
    return exp2f(x);
#endif
}
__device__ __forceinline__ float eluf(float x) {
    return x > 0.f ? x : fexp2(x * LOG2E) - 1.0f;
}
// float -> bf16 bits, round-half-up
__device__ __forceinline__ short bf16r(float x) {
    unsigned u = __float_as_uint(x);
    return (short)((u + 0x8000u) >> 16);
}
// monotone float -> sortable uint key (order-preserving for all finite values)
__device__ __forceinline__ unsigned sortkey(float x) {
    unsigned u = __float_as_uint(x);
    return u ^ (((unsigned)((int)u >> 31)) | 0x80000000u);
}
#define DOT4(c, u, p) \
    p = fmaf(c.x, u.x, fmaf(c.y, u.y, fmaf(c.z, u.z, fmaf(c.w, u.w, p))));

// ---- A: Wh = h@W via MFMA + fused f1/f2 + fused W-prep. R2-pristine
// (verified; no qpack/segzero extras). ----
__global__ __launch_bounds__(256) void k_wh(const float* __restrict__ h,
                                            const float* __restrict__ W,
                                            const float* __restrict__ a,
                                            float* __restrict__ Wh,
                                            float* __restrict__ f1,
                                            float* __restrict__ f2) {
    __shared__ __align__(16) unsigned char smem[34816];  // phase union
    short* lwt  = (short*)smem;               // A: [64 n][256 k] bf16 W^T (32 KB)
    float* lv   = (float*)(smem + 32768);     // A: [2][256] v1,v2 (2 KB)
    float* lred = (float*)smem;               // B: [4 wv][16*66] (16.9 KB)
    float* lp   = (float*)(smem + 16896);     // B: [2][4][16]

    int t = threadIdx.x;
    int wv = t >> 6, lane = t & 63;
    int n15 = lane & 15, q = lane >> 4;
    int bx = blockIdx.x;

    // issue tile-0 h loads early (independent of W staging)
    const float* hr = h + ((long)bx * 32 + n15) * KF + wv * 64 + q * 8;
    float4 c0 = *(const float4*)(hr);
    float4 c1 = *(const float4*)(hr + 4);
    float4 c2 = *(const float4*)(hr + 32);
    float4 c3 = *(const float4*)(hr + 36);

    // ---- in-block W prep: thread t owns W row k=t ----
    {
        const float4* wr4 = (const float4*)(W + t * DF);
        float s1 = 0.f, s2 = 0.f;
        #pragma unroll
        for (int c = 0; c < 16; c++) {
            float4 w4 = wr4[c];
            float4 a1v = *(const float4*)(a + 4 * c);        // uniform -> s_load
            float4 a2v = *(const float4*)(a + DF + 4 * c);
            lwt[(4 * c + 0) * 256 + t] = bf16r(w4.x);        // 2-way write: free
            lwt[(4 * c + 1) * 256 + t] = bf16r(w4.y);
            lwt[(4 * c + 2) * 256 + t] = bf16r(w4.z);
            lwt[(4 * c + 3) * 256 + t] = bf16r(w4.w);
            s1 = fmaf(w4.x, a1v.x, fmaf(w4.y, a1v.y, fmaf(w4.z, a1v.z, fmaf(w4.w, a1v.w, s1))));
            s2 = fmaf(w4.x, a2v.x, fmaf(w4.y, a2v.y, fmaf(w4.z, a2v.z, fmaf(w4.w, a2v.w, s2))));
        }
        lv[t] = s1;
        lv[256 + t] = s2;
    }
    __syncthreads();

    // hoist loop-invariant B-frags + v12 (one-time LDS reads)
    const short* bq = lwt + n15 * 256 + wv * 64 + q * 8;
    short8 s0b0 = *(const short8*)(bq);
    short8 s0b1 = *(const short8*)(bq + 16 * 256);
    short8 s0b2 = *(const short8*)(bq + 32 * 256);
    short8 s0b3 = *(const short8*)(bq + 48 * 256);
    short8 s1b0 = *(const short8*)(bq + 32);
    short8 s1b1 = *(const short8*)(bq + 16 * 256 + 32);
    short8 s1b2 = *(const short8*)(bq + 32 * 256 + 32);
    short8 s1b3 = *(const short8*)(bq + 48 * 256 + 32);
    const float* vv = lv + wv * 64 + q * 8;
    float4 u00 = *(const float4*)(vv);
    float4 u01 = *(const float4*)(vv + 4);
    float4 u10 = *(const float4*)(vv + 32);
    float4 u11 = *(const float4*)(vv + 36);
    float4 x00 = *(const float4*)(vv + 256);
    float4 x01 = *(const float4*)(vv + 256 + 4);
    float4 x10 = *(const float4*)(vv + 256 + 32);
    float4 x11 = *(const float4*)(vv + 256 + 36);
    __syncthreads();   // lwt/lv dead; lred region reusable

    #pragma unroll
    for (int rt = 0; rt < 2; rt++) {
        float4 m0, m1, m2, m3;
        if (rt < 1) {                         // prefetch next 16-row tile
            const float* hn = hr + 16 * KF;
            m0 = *(const float4*)(hn);
            m1 = *(const float4*)(hn + 4);
            m2 = *(const float4*)(hn + 32);
            m3 = *(const float4*)(hn + 36);
        }
        float p1 = 0.f, p2 = 0.f;
        DOT4(c0, u00, p1) DOT4(c1, u01, p1) DOT4(c2, u10, p1) DOT4(c3, u11, p1)
        DOT4(c0, x00, p2) DOT4(c1, x01, p2) DOT4(c2, x10, p2) DOT4(c3, x11, p2)

        short8 af0 = { bf16r(c0.x), bf16r(c0.y), bf16r(c0.z), bf16r(c0.w),
                       bf16r(c1.x), bf16r(c1.y), bf16r(c1.z), bf16r(c1.w) };
        short8 af1 = { bf16r(c2.x), bf16r(c2.y), bf16r(c2.z), bf16r(c2.w),
                       bf16r(c3.x), bf16r(c3.y), bf16r(c3.z), bf16r(c3.w) };
        float4v acc0 = {0.f, 0.f, 0.f, 0.f}, acc1 = acc0, acc2 = acc0, acc3 = acc0;
        acc0 = __builtin_amdgcn_mfma_f32_16x16x32_bf16(af0, s0b0, acc0, 0, 0, 0);
        acc0 = __builtin_amdgcn_mfma_f32_16x16x32_bf16(af1, s1b0, acc0, 0, 0, 0);
        acc1 = __builtin_amdgcn_mfma_f32_16x16x32_bf16(af0, s0b1, acc1, 0, 0, 0);
        acc1 = __builtin_amdgcn_mfma_f32_16x16x32_bf16(af1, s1b1, acc1, 0, 0, 0);
        acc2 = __builtin_amdgcn_mfma_f32_16x16x32_bf16(af0, s0b2, acc2, 0, 0, 0);
        acc2 = __builtin_amdgcn_mfma_f32_16x16x32_bf16(af1, s1b2, acc2, 0, 0, 0);
        acc3 = __builtin_amdgcn_mfma_f32_16x16x32_bf16(af0, s0b3, acc3, 0, 0, 0);
        acc3 = __builtin_amdgcn_mfma_f32_16x16x32_bf16(af1, s1b3, acc3, 0, 0, 0);

        #define STASH(nb, A)                                                  \
            {                                                                 \
                _Pragma("unroll")                                             \
                for (int r = 0; r < 4; r++)                                   \
                    lred[wv * 1056 + (q * 4 + r) * 66 + nb * 16 + n15] = A[r]; \
            }
        STASH(0, acc0) STASH(1, acc1) STASH(2, acc2) STASH(3, acc3)
        #undef STASH
        p1 += __shfl_xor(p1, 16, 64); p1 += __shfl_xor(p1, 32, 64);
        p2 += __shfl_xor(p2, 16, 64); p2 += __shfl_xor(p2, 32, 64);
        if (q == 0) { lp[wv * 16 + n15] = p1; lp[64 + wv * 16 + n15] = p2; }
        __syncthreads();

        long i0 = (long)bx * 32 + rt * 16;
        int d = t & 63, ig = t >> 6;
        int bb = (int)(i0 >> 11);
        int il = (int)(i0 & (N - 1));
        float s0 = 0.f, s1 = 0.f, s2 = 0.f, s3 = 0.f;
        #pragma unroll
        for (int w = 0; w < 4; w++) {
            const float* lr = lred + w * 1056 + (ig * 4) * 66 + d;
            s0 += lr[0]; s1 += lr[66]; s2 += lr[132]; s3 += lr[198];
        }
        float* wp = Wh + ((long)bb * N + il + ig * 4) * DF + d;
        wp[0]      = s0;
        wp[DF]     = s1;
        wp[2 * DF] = s2;
        wp[3 * DF] = s3;

        if (t < 16) {
            f1[i0 + t] = lp[t] + lp[16 + t] + lp[32 + t] + lp[48 + t];
        } else if (t < 32) {
            int tt = t + 48;   // 64 + (t-16)
            f2[i0 + t - 16] = lp[tt] + lp[16 + tt] + lp[32 + tt] + lp[48 + tt];
        }
        __syncthreads();
        c0 = m0; c1 = m1; c2 = m2; c3 = m3;
    }
}

// ---- B: brute-force ranks + denominators (R2-verified core) + the new
// inverse-map outputs that let the table kernel scatter final outputs:
//   rank2 (f2-order)  -> si / gA / gsA               [verified]
//   rank1 (f1-DESC)   -> s1i / e1pk {E1, E1s}        [new]
//   Rarr[r2+1] = N - #{i: f1_i < -f2_j}              [new; counts #{t_i < p}]
// t_i is monotone in f1, so rows with t_i == p are the contiguous f1-desc
// rank range [Rarr[p], Rarr[p+1]). Boundary ties (e==0) are value-invariant
// (both LeakyReLU branches give weight 1/den). ----
__global__ __launch_bounds__(512) void k_rank(const float* __restrict__ f1,
                                              const float* __restrict__ f2,
                                              int* __restrict__ si,
                                              float* __restrict__ gA,
                                              float* __restrict__ gsA,
                                              int* __restrict__ s1i,
                                              float2* __restrict__ e1pk,
                                              int* __restrict__ Rarr) {
    __shared__ __align__(16) float4 qv[2048];   // {f1, E1, E1s, f2}
    __shared__ unsigned u2[2048];               // sortable bits of f2
    __shared__ float rS1[8][64], rS1s[8][64];
    __shared__ int   rC1[8][64], rC2[8][64], rC4[8][64];

    int t = threadIdx.x;
    int b = blockIdx.y;
    int base = blockIdx.x * 64;
    const float* f1g = f1 + (long)b * N;
    const float* f2g = f2 + (long)b * N;

    #pragma unroll
    for (int r = 0; r < 4; r++) {
        int idx = t + r * 512;
        float v1 = f1g[idx], v2 = f2g[idx];
        qv[idx] = make_float4(v1, fexp2(v1 * LOG2E), fexp2(v1 * 0.2f * LOG2E), v2);
        u2[idx] = sortkey(v2);
    }
    __syncthreads();

    int jl = t & 63, qt = t >> 6;       // qt wave-uniform
    int j = base + jl;
    float4 qj = qv[j];
    unsigned uj = u2[j];
    unsigned u1j = sortkey(qj.x);
    float negf2 = -qj.w;
    int c1 = 0, c2 = 0, c4 = 0;
    float S1 = 0.f, S1s = 0.f;
    int p0 = qt * 256;
    #pragma unroll 4
    for (int p = p0; p < p0 + 256; p++) {
        float4 qa = qv[p];              // broadcast b128
        unsigned up = u2[p];            // broadcast b32
        unsigned u1p = sortkey(qa.x);
        c2 += (up < uj || (up == uj && p < j)) ? 1 : 0;            // f2 rank
        c1 += (u1p > u1j || (u1p == u1j && p < j)) ? 1 : 0;        // f1-desc rank
        bool cc = qa.x < negf2;          // f1_p < -f2_j
        c4 += cc ? 1 : 0;
        S1  += cc ? 0.f : qa.y;
        S1s += cc ? qa.z : 0.f;
    }
    rC1[qt][jl] = c1; rC2[qt][jl] = c2; rC4[qt][jl] = c4;
    rS1[qt][jl] = S1; rS1s[qt][jl] = S1s;
    __syncthreads();

    if (t < 64) {
        int j2 = base + t;
        float4 qj2 = qv[j2];
        int rank1 = 0, rank2 = 0, cnt4 = 0;
        float s1 = 0.f, s1s = 0.f;
        #pragma unroll
        for (int k = 0; k < 8; k++) {
            rank1 += rC1[k][t]; rank2 += rC2[k][t]; cnt4 += rC4[k][t];
            s1 += rS1[k][t];    s1s += rS1s[k][t];
        }
        float E2  = fexp2(qj2.w * LOG2E);
        float E2s = fexp2(qj2.w * 0.2f * LOG2E);
        float rr = 1.0f / (E2 * s1 + E2s * s1s);
        si [(long)b * N + rank2] = j2;          // f2-sorted order
        gA [(long)b * N + rank2] = E2 * rr;
        gsA[(long)b * N + rank2] = E2s * rr;
        Rarr[(long)b * NR + rank2 + 1] = N - cnt4;   // #{i: t_i < rank2+1}
        s1i [(long)b * N + rank1] = j2;         // f1-desc order
        e1pk[(long)b * N + rank1] = make_float2(qj2.y, qj2.z);   // {E1, E1s}
        if (blockIdx.x == 0 && t == 0) Rarr[(long)b * NR] = 0;
    }
}

// ---- C: segment sums (verified R2 body, verbatim). segG[b][seg][d] =
// sum over 32 sorted positions of g_p * Wh[si[p]][d] (and gs variant). ----
__global__ __launch_bounds__(256) void k_seg(const float* __restrict__ Wh,
                                             const int* __restrict__ si,
                                             const float* __restrict__ gA,
                                             const float* __restrict__ gsA,
                                             float* __restrict__ segG,
                                             float* __restrict__ segGs) {
    int t = threadIdx.x;
    int d = t & 63, sq = t >> 6;
    int seg = blockIdx.x * 4 + sq, b = blockIdx.y;
    const int*   sib = si  + (long)b * N;
    const float* ga  = gA  + (long)b * N;
    const float* gsa = gsA + (long)b * N;
    const float* whb = Wh + (((long)b) << 11) * DF;
    float sg = 0.f, sgs = 0.f;
    #pragma unroll 8
    for (int x = 0; x < 32; x++) {
        int p = seg * 32 + x;
        int r = sib[p];
        float wv = whb[r * DF + d];
        sg  = fmaf(ga[p],  wv, sg);
        sgs = fmaf(gsa[p], wv, sgs);
    }
    segG [(b * 64 + seg) * DF + d] = sg;
    segGs[(b * 64 + seg) * DF + d] = sgs;
}

// ---- D: table walk + DIRECT output scatter (replaces k_tab + k_out; no
// SSg/PSgs materialization). Verified k_tab prefix math; at each position p
// the running (totG - rg, rgs) pair IS the table row -> emit finished
// outputs for f1-desc ranks [Rarr[p], Rarr[p+1]) (wave-uniform bounds,
// avg 1 row/position; 256-B coalesced row stores). ----
__global__ __launch_bounds__(256) void k_tabout(const float* __restrict__ Wh,
                                                const int* __restrict__ si,
                                                const float* __restrict__ gA,
                                                const float* __restrict__ gsA,
                                                const float* __restrict__ segG,
                                                const float* __restrict__ segGs,
                                                const int* __restrict__ s1i,
                                                const float2* __restrict__ e1pk,
                                                const int* __restrict__ Rarr,
                                                float* __restrict__ out) {
    __shared__ float lPG[4][64], lPGs[4][64];   // sub-partial seg prefixes
    __shared__ float lTG[4][64];                // sub-partial seg totals
    __shared__ float wG[4][64],  wGs[4][64];    // within-seg sub sums
    int t = threadIdx.x;
    int d = t & 63, sub = t >> 6;
    int seg = blockIdx.x, b = blockIdx.y;

    const float* sgb  = segG  + (b * 64) * DF + d;
    const float* sgsb = segGs + (b * 64) * DF + d;
    float pg = 0.f, pgs = 0.f, tg = 0.f;
    #pragma unroll
    for (int k = 0; k < 16; k++) {
        int s = sub * 16 + k;
        float vg = sgb[s * DF], vgs = sgsb[s * DF];
        tg += vg;
        if (s < seg) { pg += vg; pgs += vgs; }
    }
    lPG[sub][d] = pg; lPGs[sub][d] = pgs;
    lTG[sub][d] = tg;

    int p0 = seg * 32 + sub * 8;
    const int*   sib = si  + (long)b * N;
    const float* ga  = gA  + (long)b * N;
    const float* gsa = gsA + (long)b * N;
    const float* whb = Wh + (((long)b) << 11) * DF;
    float rows[8], gv[8], gsv[8];
    float sg = 0.f, sgs = 0.f;
    #pragma unroll
    for (int x = 0; x < 8; x++) {
        int p = p0 + x;
        int r = sib[p];
        float wv = whb[r * DF + d];
        rows[x] = wv; gv[x] = ga[p]; gsv[x] = gsa[p];
        sg  = fmaf(gv[x],  wv, sg);
        sgs = fmaf(gsv[x], wv, sgs);
    }
    wG[sub][d] = sg; wGs[sub][d] = sgs;
    __syncthreads();

    float totG   = lTG[0][d] + lTG[1][d] + lTG[2][d] + lTG[3][d];
    float baseG  = lPG[0][d] + lPG[1][d] + lPG[2][d] + lPG[3][d];
    float baseGs = lPGs[0][d] + lPGs[1][d] + lPGs[2][d] + lPGs[3][d];
    #pragma unroll
    for (int k = 0; k < 3; k++) {
        if (k < sub) { baseG += wG[k][d]; baseGs += wGs[k][d]; }
    }

    const int*    Ra = Rarr + (long)b * NR;
    const int*    s1b = s1i + (long)b * N;
    const float2* e1b = e1pk + (long)b * N;
    float* ob = out + ((long)b * N) * DF + d;

    float rg = baseG, rgs = baseGs;
    #pragma unroll
    for (int x = 0; x < 8; x++) {
        int p = p0 + x;
        float ss = totG - rg;                    // SSg[p]  (suffix incl. p)
        float ps = rgs;                          // PSgs[p] (excl. prefix)
        int r0 = __builtin_amdgcn_readfirstlane(Ra[p]);
        int r1 = __builtin_amdgcn_readfirstlane(Ra[p + 1]);
        for (int rr = r0; rr < r1; rr++) {       // wave-uniform, avg 1 iter
            int row = s1b[rr];
            float2 ee = e1b[rr];
            ob[(long)row * DF] = eluf(ee.x * ss + ee.y * ps);
        }
        rg  = fmaf(gv[x],  rows[x], rg);
        rgs = fmaf(gsv[x], rows[x], rgs);
    }
    if (seg == 63 && sub == 3) {                 // position 2048: pure prefix
        float ps = rgs;
        int r0 = __builtin_amdgcn_readfirstlane(Ra[2048]);
        for (int rr = r0; rr < N; rr++) {
            int row = s1b[rr];
            float2 ee = e1b[rr];
            ob[(long)row * DF] = eluf(ee.y * ps);
        }
    }
}

extern "C" void kernel_launch(void* const* d_in, const int* in_sizes, int n_in,
                              void* d_out, int out_size, void* d_ws, size_t ws_size,
                              hipStream_t stream) {
    const float* h = (const float*)d_in[0];
    const float* W = (const float*)d_in[1];
    const float* a = (const float*)d_in[2];
    float* out = (float*)d_out;

    char* ws = (char*)d_ws;
    const size_t NB = (size_t)B * N;          // 16384 rows
    size_t off = 0;
    float*  Wh    = (float*) (ws + off); off += NB * DF * sizeof(float);   // 4 MB
    float*  f1    = (float*) (ws + off); off += NB * sizeof(float);
    float*  f2    = (float*) (ws + off); off += NB * sizeof(float);
    float*  gA    = (float*) (ws + off); off += NB * sizeof(float);
    float*  gsA   = (float*) (ws + off); off += NB * sizeof(float);
    float2* e1pk  = (float2*)(ws + off); off += NB * sizeof(float2);       // 128 KB
    int*    si    = (int*)   (ws + off); off += NB * sizeof(int);
    int*    s1i   = (int*)   (ws + off); off += NB * sizeof(int);
    int*    Rarr  = (int*)   (ws + off); off += (size_t)B * NR * sizeof(int); // 65.6 KB
    float*  segG  = (float*) (ws + off); off += (size_t)B * 64 * DF * sizeof(float); // 128 KB
    float*  segGs = (float*) (ws + off); off += (size_t)B * 64 * DF * sizeof(float);
    (void)off; (void)ws_size;

    k_wh    <<<NB / 32, 256, 0, stream>>>(h, W, a, Wh, f1, f2);
    k_rank  <<<dim3(N / 64, B), 512, 0, stream>>>(f1, f2, si, gA, gsA, s1i, e1pk, Rarr);
    k_seg   <<<dim3(16, B), 256, 0, stream>>>(Wh, si, gA, gsA, segG, segGs);
    k_tabout<<<dim3(64, B), 256, 0, stream>>>(Wh, si, gA, gsA, segG, segGs,
                                              s1i, e1pk, Rarr, out);
}